// Round 1
// baseline (2639.481 us; speedup 1.0000x reference)
//
#include <hip/hip_runtime.h>
#include <math.h>

// ---------------------------------------------------------------------------
// GraphTransformer: NL=2, H=4, C=512, IN=256, F=16, B=256, NC=47, DH=128
// fp32 correctness-first baseline. All GEMMs share one tiled kernel.
// ---------------------------------------------------------------------------

// C[M,N] = A[M,K] @ W[N,K]^T  + epilogue
// MODE 0: +bias
// MODE 1: (acc+bias) * rowa[m]                      (embedding * nmask)
// MODE 2: (acc + bias*rowa[m]) * rowb[m]            (agg-emb: sw, invden)
// MODE 3: relu(acc+bias)                            (ffn1)
// MODE 4: (acc + bias + res[m][n]) * rowa[m]        (ffn2 + residual + nmask)
template <int MODE, bool SPLITA>
__global__ __launch_bounds__(256) void gemm_kernel(
    const float* __restrict__ A, const float* __restrict__ A2, int splitK,
    const float* __restrict__ Wt, const float* __restrict__ bias,
    const float* __restrict__ res, const float* __restrict__ rowa,
    const float* __restrict__ rowb, float* __restrict__ Cout,
    int M, int N, int K) {
  __shared__ float As[16][68];
  __shared__ float Ws[16][68];
  const int t = threadIdx.x;
  const int tx = t & 15, ty = t >> 4;
  const int bm = blockIdx.x * 64, bn = blockIdx.y * 64;
  float acc[4][4] = {};
  for (int k0 = 0; k0 < K; k0 += 16) {
#pragma unroll
    for (int r = 0; r < 4; ++r) {
      const int row = ty + r * 16;  // 0..63
      const int gm = bm + row, gn = bn + row, gk = k0 + tx;
      float av = 0.f;
      if (gm < M) {
        if (SPLITA)
          av = (gk < splitK) ? A[(size_t)gm * splitK + gk]
                             : A2[(size_t)gm * (K - splitK) + gk - splitK];
        else
          av = A[(size_t)gm * K + gk];
      }
      As[tx][row] = av;
      Ws[tx][row] = (gn < N) ? Wt[(size_t)gn * K + gk] : 0.f;
    }
    __syncthreads();
#pragma unroll
    for (int k = 0; k < 16; ++k) {
      const float4 a4 = *reinterpret_cast<const float4*>(&As[k][ty * 4]);
      const float4 b4 = *reinterpret_cast<const float4*>(&Ws[k][tx * 4]);
      const float a[4] = {a4.x, a4.y, a4.z, a4.w};
      const float b[4] = {b4.x, b4.y, b4.z, b4.w};
#pragma unroll
      for (int i = 0; i < 4; ++i)
#pragma unroll
        for (int j = 0; j < 4; ++j) acc[i][j] = fmaf(a[i], b[j], acc[i][j]);
    }
    __syncthreads();
  }
#pragma unroll
  for (int i = 0; i < 4; ++i) {
    const int m = bm + ty * 4 + i;
    if (m >= M) continue;
#pragma unroll
    for (int j = 0; j < 4; ++j) {
      const int n = bn + tx * 4 + j;
      if (n >= N) continue;
      float v = acc[i][j];
      if (MODE == 0) v += bias[n];
      if (MODE == 1) v = (v + bias[n]) * rowa[m];
      if (MODE == 2) v = (v + bias[n] * rowa[m]) * rowb[m];
      if (MODE == 3) v = fmaxf(v + bias[n], 0.f);
      if (MODE == 4) v = (v + bias[n] + res[(size_t)m * N + n]) * rowa[m];
      Cout[(size_t)m * N + n] = v;
    }
  }
}

// out[row] = LN(X[row] + Y[row]) * g + b   (row length 512)
__global__ __launch_bounds__(256) void add_ln_kernel(
    const float* __restrict__ X, const float* __restrict__ Y,
    const float* __restrict__ g, const float* __restrict__ b,
    float* __restrict__ out) {
  const int row = blockIdx.x;
  const int t = threadIdx.x;
  const size_t base = (size_t)row * 512;
  const float x0 = X[base + t] + Y[base + t];
  const float x1 = X[base + 256 + t] + Y[base + 256 + t];
  float s = x0 + x1, ss = x0 * x0 + x1 * x1;
#pragma unroll
  for (int o = 32; o > 0; o >>= 1) {
    s += __shfl_down(s, o);
    ss += __shfl_down(ss, o);
  }
  __shared__ float rs[4], rss[4];
  __shared__ float smean, srstd;
  const int wave = t >> 6, lane = t & 63;
  if (lane == 0) { rs[wave] = s; rss[wave] = ss; }
  __syncthreads();
  if (t == 0) {
    const float S = rs[0] + rs[1] + rs[2] + rs[3];
    const float SS = rss[0] + rss[1] + rss[2] + rss[3];
    const float mean = S * (1.f / 512.f);
    const float var = SS * (1.f / 512.f) - mean * mean;
    smean = mean;
    srstd = rsqrtf(var + 1e-5f);
  }
  __syncthreads();
  const float mean = smean, rstd = srstd;
  out[base + t] = (x0 - mean) * rstd * g[t] + b[t];
  out[base + 256 + t] = (x1 - mean) * rstd * g[t + 256] + b[t + 256];
}

// aggF[i,:] = sum_j nb1[i,j]*nm2[i*16+j]*feats2[i*16+j,:]; sw = sum w; invd = 1/max(sum nb,1)
__global__ __launch_bounds__(256) void agg_feats_kernel(
    const float* __restrict__ feats2, const int* __restrict__ nbmask1,
    const float* __restrict__ nmask2, float* __restrict__ aggF,
    float* __restrict__ sw, float* __restrict__ invden) {
  const int i = blockIdx.x;   // 0..4095
  const int t = threadIdx.x;  // 0..255
  float acc = 0.f, wsum = 0.f, nbsum = 0.f;
#pragma unroll
  for (int j = 0; j < 16; ++j) {
    const float nb = (float)nbmask1[i * 16 + j];
    const float w = nb * nmask2[i * 16 + j];
    acc += w * feats2[(size_t)(i * 16 + j) * 256 + t];
    wsum += w;
    nbsum += nb;
  }
  aggF[(size_t)i * 256 + t] = acc;
  if (t == 0) {
    sw[i] = wsum;
    invden[i] = 1.f / fmaxf(nbsum, 1.f);
  }
}

// agg[i,:] = sum_j nb0[i,j]*src[i*16+j,:] / max(sum nb,1)   (C=512)
__global__ __launch_bounds__(256) void agg_state_kernel(
    const float* __restrict__ src, const int* __restrict__ nbmask0,
    float* __restrict__ agg) {
  const int i = blockIdx.x;   // 0..255
  const int t = threadIdx.x;  // 0..255
  float a0 = 0.f, a1 = 0.f, nbsum = 0.f;
#pragma unroll
  for (int j = 0; j < 16; ++j) {
    const float nb = (float)nbmask0[i * 16 + j];
    const float* r = src + (size_t)(i * 16 + j) * 512;
    a0 += nb * r[t];
    a1 += nb * r[t + 256];
    nbsum += nb;
  }
  const float inv = 1.f / fmaxf(nbsum, 1.f);
  agg[(size_t)i * 512 + t] = a0 * inv;
  agg[(size_t)i * 512 + 256 + t] = a1 * inv;
}

// Flash attention: qkv [N,1536] (Q|K|V, head h at cols h*128), out attno [N,512]
__global__ __launch_bounds__(256) void flash_kernel(
    const float* __restrict__ qkv, float* __restrict__ attno, int N) {
  const int qb = blockIdx.x;
  const int head = blockIdx.y;
  const int t = threadIdx.x;
  const int tx = t & 15, ty = t >> 4;
  __shared__ float Qs[64][129];
  __shared__ float Ks[64][129];
  __shared__ float Vs[64][132];
  __shared__ float Sb[64][65];
  __shared__ float mrun[64], lrun[64], frow[64], red[4][64];
  const float scale = 0.08838834764831845f;  // 1/sqrt(128)

  // load Q block
  for (int e = t * 4; e < 64 * 128; e += 1024) {
    const int r = e >> 7, d = e & 127;
    const float4 q4 = *reinterpret_cast<const float4*>(
        &qkv[(size_t)(qb * 64 + r) * 1536 + head * 128 + d]);
    Qs[r][d] = q4.x; Qs[r][d + 1] = q4.y; Qs[r][d + 2] = q4.z; Qs[r][d + 3] = q4.w;
  }
  if (t < 64) { mrun[t] = -1e30f; lrun[t] = 0.f; }

  float o[4][8] = {};
  const int nkb = N >> 6;
  for (int kb = 0; kb < nkb; ++kb) {
    __syncthreads();  // covers Q/stat init and prev PV before overwriting K/V
    for (int e = t * 4; e < 64 * 128; e += 1024) {
      const int r = e >> 7, d = e & 127;
      const size_t rowb = (size_t)(kb * 64 + r) * 1536 + head * 128 + d;
      const float4 k4 = *reinterpret_cast<const float4*>(&qkv[rowb + 512]);
      Ks[r][d] = k4.x; Ks[r][d + 1] = k4.y; Ks[r][d + 2] = k4.z; Ks[r][d + 3] = k4.w;
      const float4 v4 = *reinterpret_cast<const float4*>(&qkv[rowb + 1024]);
      *reinterpret_cast<float4*>(&Vs[r][d]) = v4;
    }
    __syncthreads();
    // S = Q @ K^T
    float s[4][4] = {};
#pragma unroll 4
    for (int d = 0; d < 128; ++d) {
      const float q0 = Qs[ty * 4 + 0][d], q1 = Qs[ty * 4 + 1][d];
      const float q2 = Qs[ty * 4 + 2][d], q3 = Qs[ty * 4 + 3][d];
      const float k0 = Ks[tx * 4 + 0][d], k1 = Ks[tx * 4 + 1][d];
      const float k2 = Ks[tx * 4 + 2][d], k3 = Ks[tx * 4 + 3][d];
      s[0][0] = fmaf(q0, k0, s[0][0]); s[0][1] = fmaf(q0, k1, s[0][1]);
      s[0][2] = fmaf(q0, k2, s[0][2]); s[0][3] = fmaf(q0, k3, s[0][3]);
      s[1][0] = fmaf(q1, k0, s[1][0]); s[1][1] = fmaf(q1, k1, s[1][1]);
      s[1][2] = fmaf(q1, k2, s[1][2]); s[1][3] = fmaf(q1, k3, s[1][3]);
      s[2][0] = fmaf(q2, k0, s[2][0]); s[2][1] = fmaf(q2, k1, s[2][1]);
      s[2][2] = fmaf(q2, k2, s[2][2]); s[2][3] = fmaf(q2, k3, s[2][3]);
      s[3][0] = fmaf(q3, k0, s[3][0]); s[3][1] = fmaf(q3, k1, s[3][1]);
      s[3][2] = fmaf(q3, k2, s[3][2]); s[3][3] = fmaf(q3, k3, s[3][3]);
    }
#pragma unroll
    for (int i = 0; i < 4; ++i)
#pragma unroll
      for (int j = 0; j < 4; ++j) Sb[ty * 4 + i][tx * 4 + j] = s[i][j] * scale;
    __syncthreads();
    // row max (4 partials per row)
    {
      const int r = t & 63, q = t >> 6;
      float pm = -1e30f;
#pragma unroll
      for (int c = 0; c < 16; ++c) pm = fmaxf(pm, Sb[r][q * 16 + c]);
      red[q][r] = pm;
    }
    __syncthreads();
    if (t < 64) {
      const float mnew = fmaxf(
          fmaxf(fmaxf(red[0][t], red[1][t]), fmaxf(red[2][t], red[3][t])),
          mrun[t]);
      const float f = __expf(mrun[t] - mnew);
      mrun[t] = mnew;
      frow[t] = f;
      lrun[t] *= f;
    }
    __syncthreads();
    // exp pass + partial sums
    {
      const int r = t & 63, q = t >> 6;
      const float m = mrun[r];
      float ps = 0.f;
#pragma unroll
      for (int c = 0; c < 16; ++c) {
        const float p = __expf(Sb[r][q * 16 + c] - m);
        Sb[r][q * 16 + c] = p;
        ps += p;
      }
      red[q][r] = ps;
    }
    // rescale O (registers only)
    {
      float fr[4];
#pragma unroll
      for (int i = 0; i < 4; ++i) fr[i] = frow[ty * 4 + i];
#pragma unroll
      for (int i = 0; i < 4; ++i)
#pragma unroll
        for (int j = 0; j < 8; ++j) o[i][j] *= fr[i];
    }
    __syncthreads();
    if (t < 64) lrun[t] += red[0][t] + red[1][t] + red[2][t] + red[3][t];
    // O += P @ V
#pragma unroll 2
    for (int k = 0; k < 64; ++k) {
      const float p0 = Sb[ty * 4 + 0][k], p1 = Sb[ty * 4 + 1][k];
      const float p2 = Sb[ty * 4 + 2][k], p3 = Sb[ty * 4 + 3][k];
      const float4 va = *reinterpret_cast<const float4*>(&Vs[k][tx * 8]);
      const float4 vb = *reinterpret_cast<const float4*>(&Vs[k][tx * 8 + 4]);
      o[0][0] = fmaf(p0, va.x, o[0][0]); o[0][1] = fmaf(p0, va.y, o[0][1]);
      o[0][2] = fmaf(p0, va.z, o[0][2]); o[0][3] = fmaf(p0, va.w, o[0][3]);
      o[0][4] = fmaf(p0, vb.x, o[0][4]); o[0][5] = fmaf(p0, vb.y, o[0][5]);
      o[0][6] = fmaf(p0, vb.z, o[0][6]); o[0][7] = fmaf(p0, vb.w, o[0][7]);
      o[1][0] = fmaf(p1, va.x, o[1][0]); o[1][1] = fmaf(p1, va.y, o[1][1]);
      o[1][2] = fmaf(p1, va.z, o[1][2]); o[1][3] = fmaf(p1, va.w, o[1][3]);
      o[1][4] = fmaf(p1, vb.x, o[1][4]); o[1][5] = fmaf(p1, vb.y, o[1][5]);
      o[1][6] = fmaf(p1, vb.z, o[1][6]); o[1][7] = fmaf(p1, vb.w, o[1][7]);
      o[2][0] = fmaf(p2, va.x, o[2][0]); o[2][1] = fmaf(p2, va.y, o[2][1]);
      o[2][2] = fmaf(p2, va.z, o[2][2]); o[2][3] = fmaf(p2, va.w, o[2][3]);
      o[2][4] = fmaf(p2, vb.x, o[2][4]); o[2][5] = fmaf(p2, vb.y, o[2][5]);
      o[2][6] = fmaf(p2, vb.z, o[2][6]); o[2][7] = fmaf(p2, vb.w, o[2][7]);
      o[3][0] = fmaf(p3, va.x, o[3][0]); o[3][1] = fmaf(p3, va.y, o[3][1]);
      o[3][2] = fmaf(p3, va.z, o[3][2]); o[3][3] = fmaf(p3, va.w, o[3][3]);
      o[3][4] = fmaf(p3, vb.x, o[3][4]); o[3][5] = fmaf(p3, vb.y, o[3][5]);
      o[3][6] = fmaf(p3, vb.z, o[3][6]); o[3][7] = fmaf(p3, vb.w, o[3][7]);
    }
  }
  __syncthreads();
#pragma unroll
  for (int i = 0; i < 4; ++i) {
    const int r = ty * 4 + i;
    const float inv = 1.f / lrun[r];
#pragma unroll
    for (int j = 0; j < 8; ++j)
      attno[(size_t)(qb * 64 + r) * 512 + head * 128 + tx * 8 + j] =
          o[i][j] * inv;
  }
}

// ---------------------------------------------------------------------------

static inline dim3 g2(int M, int N) { return dim3((M + 63) / 64, (N + 63) / 64); }

struct BlockBufs {
  float *tmp, *h1, *h2, *bufA, *attno;
};

static void transformer_block(int n, const float* sf, const float* agg,
                              const float* nmask, const float* sage_w,
                              const float* sage_b, const float* qkv_w,
                              const float* qkv_b, const float* out_w,
                              const float* out_b, const float* n1g,
                              const float* n1b, const float* n2g,
                              const float* n2b, const float* f1w,
                              const float* f1b, const float* f2w,
                              const float* f2b, const BlockBufs& B,
                              float* s_out, hipStream_t stream) {
  // h_local = [sf|agg] @ sage_w^T + sage_b
  gemm_kernel<0, true><<<g2(n, 512), 256, 0, stream>>>(
      sf, agg, 512, sage_w, sage_b, nullptr, nullptr, nullptr, B.tmp, n, 512, 1024);
  // h1 = LN(sf + h_local)
  add_ln_kernel<<<n, 256, 0, stream>>>(sf, B.tmp, n1g, n1b, B.h1);
  // qkv
  gemm_kernel<0, false><<<g2(n, 1536), 256, 0, stream>>>(
      B.h1, nullptr, 0, qkv_w, qkv_b, nullptr, nullptr, nullptr, B.bufA, n, 1536, 512);
  // attention
  flash_kernel<<<dim3(n / 64, 4), 256, 0, stream>>>(B.bufA, B.attno, n);
  // out proj
  gemm_kernel<0, false><<<g2(n, 512), 256, 0, stream>>>(
      B.attno, nullptr, 0, out_w, out_b, nullptr, nullptr, nullptr, B.tmp, n, 512, 512);
  // h2 = LN(h1 + proj)
  add_ln_kernel<<<n, 256, 0, stream>>>(B.h1, B.tmp, n2g, n2b, B.h2);
  // ffn1 (relu)
  gemm_kernel<3, false><<<g2(n, 1024), 256, 0, stream>>>(
      B.h2, nullptr, 0, f1w, f1b, nullptr, nullptr, nullptr, B.bufA, n, 1024, 512);
  // ffn2 + residual + nmask
  gemm_kernel<4, false><<<g2(n, 512), 256, 0, stream>>>(
      B.bufA, nullptr, 0, f2w, f2b, B.h2, nmask, nullptr, s_out, n, 512, 1024);
}

extern "C" void kernel_launch(void* const* d_in, const int* in_sizes, int n_in,
                              void* d_out, int out_size, void* d_ws,
                              size_t ws_size, hipStream_t stream) {
  const float* feats0 = (const float*)d_in[0];
  const float* feats1 = (const float*)d_in[1];
  const float* feats2 = (const float*)d_in[2];
  const float* nmask0 = (const float*)d_in[3];
  const float* nmask1 = (const float*)d_in[4];
  const float* nmask2 = (const float*)d_in[5];
  const int* nbmask0 = (const int*)d_in[6];
  const int* nbmask1 = (const int*)d_in[7];
  const float* emb_w = (const float*)d_in[8];
  const float* emb_b = (const float*)d_in[9];
  const float* sage_w = (const float*)d_in[10];
  const float* sage_b = (const float*)d_in[11];
  const float* qkv_w = (const float*)d_in[12];
  const float* qkv_b = (const float*)d_in[13];
  const float* out_w = (const float*)d_in[14];
  const float* out_b = (const float*)d_in[15];
  const float* n1_g = (const float*)d_in[16];
  const float* n1_b = (const float*)d_in[17];
  const float* n2_g = (const float*)d_in[18];
  const float* n2_b = (const float*)d_in[19];
  const float* ffn_w1 = (const float*)d_in[20];
  const float* ffn_b1 = (const float*)d_in[21];
  const float* ffn_w2 = (const float*)d_in[22];
  const float* ffn_b2 = (const float*)d_in[23];
  const float* cls_w = (const float*)d_in[24];
  const float* cls_b = (const float*)d_in[25];
  float* out = (float*)d_out;

  float* w = (float*)d_ws;
  float* s0 = w;    w += 256 * 512;
  float* s1 = w;    w += 4096 * 512;
  float* s0b = w;   w += 256 * 512;
  float* s1b = w;   w += 4096 * 512;
  float* aggF = w;  w += 4096 * 256;
  float* swv = w;   w += 4096;
  float* invd = w;  w += 4096;
  float* agg = w;   w += 4096 * 512;
  float* bufA = w;  w += 4096 * 1536;
  float* tmp = w;   w += 4096 * 512;
  float* h1 = w;    w += 4096 * 512;
  float* h2 = w;    w += 4096 * 512;
  float* attno = w; w += 4096 * 512;

  BlockBufs B{tmp, h1, h2, bufA, attno};

  // embeddings (depth 0 and 1); depth 2 is folded into the aggregation below
  gemm_kernel<1, false><<<g2(256, 512), 256, 0, stream>>>(
      feats0, nullptr, 0, emb_w, emb_b, nullptr, nmask0, nullptr, s0, 256, 512, 256);
  gemm_kernel<1, false><<<g2(4096, 512), 256, 0, stream>>>(
      feats1, nullptr, 0, emb_w, emb_b, nullptr, nmask1, nullptr, s1, 4096, 512, 256);

  // ---- layer 0, depth 1 (n=4096) ----
  agg_feats_kernel<<<4096, 256, 0, stream>>>(feats2, nbmask1, nmask2, aggF, swv, invd);
  gemm_kernel<2, false><<<g2(4096, 512), 256, 0, stream>>>(
      aggF, nullptr, 0, emb_w, emb_b, nullptr, swv, invd, agg, 4096, 512, 256);
  transformer_block(4096, s1, agg, nmask1, sage_w, sage_b, qkv_w, qkv_b, out_w,
                    out_b, n1_g, n1_b, n2_g, n2_b, ffn_w1, ffn_b1, ffn_w2,
                    ffn_b2, B, s1b, stream);

  // ---- layer 0, depth 0 (n=256), children = OLD s1 ----
  agg_state_kernel<<<256, 256, 0, stream>>>(s1, nbmask0, agg);
  transformer_block(256, s0, agg, nmask0, sage_w, sage_b, qkv_w, qkv_b, out_w,
                    out_b, n1_g, n1_b, n2_g, n2_b, ffn_w1, ffn_b1, ffn_w2,
                    ffn_b2, B, s0b, stream);

  // ---- layer 1, depth 0 (n=256), children = s1b ----
  const float* sage_w1 = sage_w + 512 * 1024;
  const float* sage_b1 = sage_b + 512;
  const float* qkv_w1 = qkv_w + 1536 * 512;
  const float* qkv_b1 = qkv_b + 1536;
  const float* out_w1 = out_w + 512 * 512;
  const float* out_b1 = out_b + 512;
  const float* n1_g1 = n1_g + 512;
  const float* n1_b1 = n1_b + 512;
  const float* n2_g1 = n2_g + 512;
  const float* n2_b1 = n2_b + 512;
  const float* ffn_w11 = ffn_w1 + 1024 * 512;
  const float* ffn_b11 = ffn_b1 + 1024;
  const float* ffn_w21 = ffn_w2 + 512 * 1024;
  const float* ffn_b21 = ffn_b2 + 512;
  agg_state_kernel<<<256, 256, 0, stream>>>(s1b, nbmask0, agg);
  transformer_block(256, s0b, agg, nmask0, sage_w1, sage_b1, qkv_w1, qkv_b1,
                    out_w1, out_b1, n1_g1, n1_b1, n2_g1, n2_b1, ffn_w11,
                    ffn_b11, ffn_w21, ffn_b21, B, s0, stream);

  // classifier
  gemm_kernel<0, false><<<g2(256, 47), 256, 0, stream>>>(
      s0, nullptr, 0, cls_w, cls_b, nullptr, nullptr, nullptr, out, 256, 47, 512);
}

// Round 2
// 383.679 us; speedup vs baseline: 6.8794x; 6.8794x over previous
//
#include <hip/hip_runtime.h>
#include <math.h>

// ---------------------------------------------------------------------------
// GraphTransformer, bf16 MFMA version.
// NL=2, H=4, C=512, IN=256, F=16, B=256, NC=47, DH=128
// ---------------------------------------------------------------------------

typedef unsigned short bf16_t;
typedef __attribute__((ext_vector_type(8))) short bf16x8_t;
typedef __attribute__((ext_vector_type(4))) float f32x4_t;

__device__ __forceinline__ bf16_t f2bf(float f) {
  union { float f; unsigned u; } v; v.f = f;
  unsigned r = v.u + 0x7FFFu + ((v.u >> 16) & 1u);
  return (bf16_t)(r >> 16);
}
__device__ __forceinline__ float bf2f(bf16_t u) {
  union { unsigned u; float f; } v; v.u = ((unsigned)u) << 16; return v.f;
}
__device__ __forceinline__ void gload16(const void* g, void* l) {
  __builtin_amdgcn_global_load_lds(
      (const __attribute__((address_space(1))) unsigned int*)g,
      (__attribute__((address_space(3))) unsigned int*)l, 16, 0, 0);
}

// ---------------------------------------------------------------------------
// GEMM: C[M,N] = A[M,K] @ W[N,K]^T + epilogue. A,W bf16; accum fp32.
// MODE 0: Cf = acc + b                      (fp32 out)
// MODE 1: Cb = (acc + b) * rowa[m]          (embedding * nmask)
// MODE 2: Cb = (acc + b*rowa[m]) * rowb[m]  (agg-emb)
// MODE 3: Cb = relu(acc + b)                (ffn1)
// MODE 4: Cb = (acc + b + res[m,n]) * rowa[m]  (ffn2 + residual + nmask)
// MODE 5: qkv: cols<512 -> Cb[m,1024] scaled; <1024 -> Cb; >=1024 -> Vt[n-1024, m]
// SPLIT: A = concat(A[M,512], A2[M,512]) along K (K=1024).
// ---------------------------------------------------------------------------
template <int BM, int BN, int MODE, bool SPLIT>
__global__ __launch_bounds__(256) void mgemm(
    const bf16_t* __restrict__ A, const bf16_t* __restrict__ A2,
    const bf16_t* __restrict__ W, const float* __restrict__ bias,
    const bf16_t* __restrict__ res, const float* __restrict__ rowa,
    const float* __restrict__ rowb, float* __restrict__ Cf,
    bf16_t* __restrict__ Cb, bf16_t* __restrict__ Vt,
    int M, int N, int K) {
  constexpr int FM = BM / 32, FN = BN / 32;
  constexpr int NCH = (BM + BN) / 16;  // 1KB staging chunks per k-step
  constexpr int CPW = NCH / 4;
  __shared__ bf16_t lds[2][(BM + BN) * 32];
  const int t = threadIdx.x;
  const int w = t >> 6, lane = t & 63;
  const int g = lane >> 4, li = lane & 15;
  const int bm = blockIdx.x * BM, bn = blockIdx.y * BN;
  const int wr = (w >> 1) * (BM / 2), wc = (w & 1) * (BN / 2);
  f32x4_t acc[FM][FN] = {};

  auto stage = [&](int buf, int k0) {
#pragma unroll
    for (int c0 = 0; c0 < CPW; ++c0) {
      const int c = w * CPW + c0;
      const int row = c * 16 + (lane >> 2);
      const int gk = k0 + (lane & 3) * 8;
      const bf16_t* src;
      if (row < BM) {
        if (SPLIT) {
          src = (gk < 512) ? (A + (size_t)(bm + row) * 512 + gk)
                           : (A2 + (size_t)(bm + row) * 512 + (gk - 512));
        } else {
          src = A + (size_t)(bm + row) * K + gk;
        }
      } else {
        src = W + (size_t)(bn + row - BM) * K + gk;
      }
      gload16(src, &lds[buf][c * 512]);
    }
  };

  const int nk = K / 32;
  stage(0, 0);
  for (int ks = 0; ks < nk; ++ks) {
    __syncthreads();
    if (ks + 1 < nk) stage((ks + 1) & 1, (ks + 1) * 32);
    const bf16_t* As = &lds[ks & 1][0];
    const bf16_t* Bs = &lds[ks & 1][BM * 32];
    bf16x8_t af[FM], bfr[FN];
#pragma unroll
    for (int i = 0; i < FM; ++i)
      af[i] = *(const bf16x8_t*)(As + (wr + i * 16 + li) * 32 + g * 8);
#pragma unroll
    for (int j = 0; j < FN; ++j)
      bfr[j] = *(const bf16x8_t*)(Bs + (wc + j * 16 + li) * 32 + g * 8);
#pragma unroll
    for (int i = 0; i < FM; ++i)
#pragma unroll
      for (int j = 0; j < FN; ++j)
        acc[i][j] = __builtin_amdgcn_mfma_f32_16x16x32_bf16(
            af[i], bfr[j], acc[i][j], 0, 0, 0);
  }

  // epilogue: D frag: col n = li, row m = g*4 + reg (verified layout)
#pragma unroll
  for (int i = 0; i < FM; ++i) {
    const int mb = bm + wr + i * 16 + g * 4;
#pragma unroll
    for (int j = 0; j < FN; ++j) {
      const int n = bn + wc + j * 16 + li;
      if (MODE == 5) {
        const float bb = bias[n];
        if (n < 512) {
#pragma unroll
          for (int r = 0; r < 4; ++r)
            Cb[(size_t)(mb + r) * 1024 + n] =
                f2bf((acc[i][j][r] + bb) * 0.08838834764831845f);
        } else if (n < 1024) {
#pragma unroll
          for (int r = 0; r < 4; ++r)
            Cb[(size_t)(mb + r) * 1024 + n] = f2bf(acc[i][j][r] + bb);
        } else {
          ushort4 o;
          o.x = f2bf(acc[i][j][0] + bb); o.y = f2bf(acc[i][j][1] + bb);
          o.z = f2bf(acc[i][j][2] + bb); o.w = f2bf(acc[i][j][3] + bb);
          *(ushort4*)(Vt + (size_t)(n - 1024) * M + mb) = o;
        }
      } else {
#pragma unroll
        for (int r = 0; r < 4; ++r) {
          const int m = mb + r;
          const float v = acc[i][j][r];
          if (MODE == 0) Cf[(size_t)m * N + n] = v + bias[n];
          if (MODE == 1) Cb[(size_t)m * N + n] = f2bf((v + bias[n]) * rowa[m]);
          if (MODE == 2)
            Cb[(size_t)m * N + n] = f2bf((v + bias[n] * rowa[m]) * rowb[m]);
          if (MODE == 3) Cb[(size_t)m * N + n] = f2bf(fmaxf(v + bias[n], 0.f));
          if (MODE == 4)
            Cb[(size_t)m * N + n] =
                f2bf((v + bias[n] + bf2f(res[(size_t)m * N + n])) * rowa[m]);
        }
      }
    }
  }
}

// ---------------------------------------------------------------------------
// Flash attention, swapped-operand form.
// qk: [N][1024] = Q(scaled)|K, head h at cols h*128. vt: [512][N] = V^T.
// Per block: one (head, 64-row q-block). 4 waves, wave w owns q rows w*16..+15.
// S^T = K·Q^T  (lane li holds full row q=li across 16 regs)
// O^T = Vt·P^T, accumulators 128d x 16q per wave.
// ---------------------------------------------------------------------------
__global__ __launch_bounds__(256) void flashT(
    const bf16_t* __restrict__ qk, const bf16_t* __restrict__ vt,
    bf16_t* __restrict__ attno, int N) {
  __shared__ bf16_t Ks[2][64 * 128];
  __shared__ bf16_t Vs[2][128 * 64];
  __shared__ bf16_t Ps[4][16 * 64];
  const int bid = blockIdx.x;
  const int h = (bid >> 1) & 3;              // XCD-pair per head
  const int qb = (bid >> 3) * 2 + (bid & 1);
  const int t = threadIdx.x, w = t >> 6, lane = t & 63;
  const int g = lane >> 4, li = lane & 15;

  bf16x8_t qf[4];
  {
    const bf16_t* qrow = qk + (size_t)(qb * 64 + w * 16 + li) * 1024 + h * 128;
#pragma unroll
    for (int ks = 0; ks < 4; ++ks)
      qf[ks] = *(const bf16x8_t*)(qrow + ks * 32 + g * 8);
  }

  auto stage = [&](int buf, int kv0) {
#pragma unroll
    for (int i = 0; i < 4; ++i) {
      const int c = w * 4 + i;
      {  // K tile: 64 rows(kv) x 128 d, xor-swizzled 16B chunks
        const int row = c * 4 + (lane >> 4);
        const int col = ((lane & 15) ^ (row & 7)) * 8;
        gload16(qk + (size_t)(kv0 + row) * 1024 + 512 + h * 128 + col,
                &Ks[buf][c * 512]);
      }
      {  // Vt tile: 128 rows(d) x 64 kv, xor-swizzled
        const int row = c * 8 + (lane >> 3);
        const int col = ((lane & 7) ^ (row & 7)) * 8;
        gload16(vt + (size_t)(h * 128 + row) * N + kv0 + col,
                &Vs[buf][c * 512]);
      }
    }
  };

  f32x4_t acc[8] = {};
  float mrun = -1e30f, lrun = 0.f;
  const int nt = N >> 6;
  stage(0, 0);
  for (int tt = 0; tt < nt; ++tt) {
    const int cur = tt & 1;
    __syncthreads();
    if (tt + 1 < nt) stage(cur ^ 1, (tt + 1) * 64);

    // S^T = K · Q^T : frag row kv = mf*16+g*4+r, col q = li
    f32x4_t sf[4] = {};
#pragma unroll
    for (int ks = 0; ks < 4; ++ks) {
#pragma unroll
      for (int mf = 0; mf < 4; ++mf) {
        const bf16x8_t kf = *(const bf16x8_t*)(
            &Ks[cur][(mf * 16 + li) * 128 + (((ks * 4 + g) ^ (li & 7)) << 3)]);
        sf[mf] =
            __builtin_amdgcn_mfma_f32_16x16x32_bf16(kf, qf[ks], sf[mf], 0, 0, 0);
      }
    }
    // online softmax: lane li owns q-row li; kv spread over 4 lane-groups
    float tmax = -1e30f;
#pragma unroll
    for (int mf = 0; mf < 4; ++mf)
#pragma unroll
      for (int r = 0; r < 4; ++r) tmax = fmaxf(tmax, sf[mf][r]);
    tmax = fmaxf(tmax, __shfl_xor(tmax, 16));
    tmax = fmaxf(tmax, __shfl_xor(tmax, 32));
    const float mnew = fmaxf(mrun, tmax);
    const float fsc = __expf(mrun - mnew);
    mrun = mnew;
    float lsum = 0.f;
#pragma unroll
    for (int mf = 0; mf < 4; ++mf)
#pragma unroll
      for (int r = 0; r < 4; ++r) {
        const float p = __expf(sf[mf][r] - mnew);
        sf[mf][r] = p;
        lsum += p;
      }
    lsum += __shfl_xor(lsum, 16);
    lsum += __shfl_xor(lsum, 32);
    lrun = lrun * fsc + lsum;
#pragma unroll
    for (int mf = 0; mf < 8; ++mf) acc[mf] *= fsc;

    // P -> per-wave LDS (bf16, swizzled); chunk c holds kv c*8..c*8+7
#pragma unroll
    for (int mf = 0; mf < 4; ++mf) {
      uint2 pv;
      pv.x = (unsigned)f2bf(sf[mf][0]) | ((unsigned)f2bf(sf[mf][1]) << 16);
      pv.y = (unsigned)f2bf(sf[mf][2]) | ((unsigned)f2bf(sf[mf][3]) << 16);
      *(uint2*)(&Ps[w][li * 64 + ((((mf * 2) + (g >> 1)) ^ (li & 7)) << 3) +
                       ((g & 1) << 2)]) = pv;
    }
    // O^T += Vt · P^T
#pragma unroll
    for (int ks = 0; ks < 2; ++ks) {
      const bf16x8_t pf = *(const bf16x8_t*)(
          &Ps[w][li * 64 + (((ks * 4 + g) ^ (li & 7)) << 3)]);
#pragma unroll
      for (int mf = 0; mf < 8; ++mf) {
        const bf16x8_t vf = *(const bf16x8_t*)(
            &Vs[cur][(mf * 16 + li) * 64 + (((ks * 4 + g) ^ (li & 7)) << 3)]);
        acc[mf] =
            __builtin_amdgcn_mfma_f32_16x16x32_bf16(vf, pf, acc[mf], 0, 0, 0);
      }
    }
  }
  const float invl = 1.f / lrun;
#pragma unroll
  for (int mf = 0; mf < 8; ++mf) {
    ushort4 o;
    o.x = f2bf(acc[mf][0] * invl); o.y = f2bf(acc[mf][1] * invl);
    o.z = f2bf(acc[mf][2] * invl); o.w = f2bf(acc[mf][3] * invl);
    *(ushort4*)(attno + (size_t)(qb * 64 + w * 16 + li) * 512 + h * 128 +
                mf * 16 + g * 4) = o;
  }
}

// ---------------------------------------------------------------------------
__global__ __launch_bounds__(256) void add_ln(
    const bf16_t* __restrict__ X, const float* __restrict__ Y,
    const float* __restrict__ gg, const float* __restrict__ bb,
    bf16_t* __restrict__ out) {
  const int row = blockIdx.x, t = threadIdx.x;
  const size_t base = (size_t)row * 512;
  const float x0 = bf2f(X[base + t]) + Y[base + t];
  const float x1 = bf2f(X[base + 256 + t]) + Y[base + 256 + t];
  float s = x0 + x1, ss = x0 * x0 + x1 * x1;
#pragma unroll
  for (int o = 32; o > 0; o >>= 1) {
    s += __shfl_down(s, o);
    ss += __shfl_down(ss, o);
  }
  __shared__ float rs[4], rss[4], sm[2];
  const int wv = t >> 6, ln = t & 63;
  if (ln == 0) { rs[wv] = s; rss[wv] = ss; }
  __syncthreads();
  if (t == 0) {
    const float S = rs[0] + rs[1] + rs[2] + rs[3];
    const float SS = rss[0] + rss[1] + rss[2] + rss[3];
    const float mean = S * (1.f / 512.f);
    sm[0] = mean;
    sm[1] = rsqrtf(SS * (1.f / 512.f) - mean * mean + 1e-5f);
  }
  __syncthreads();
  const float mean = sm[0], rstd = sm[1];
  out[base + t] = f2bf((x0 - mean) * rstd * gg[t] + bb[t]);
  out[base + 256 + t] = f2bf((x1 - mean) * rstd * gg[t + 256] + bb[t + 256]);
}

__global__ __launch_bounds__(256) void agg_feats(
    const float* __restrict__ feats2, const int* __restrict__ nbm,
    const float* __restrict__ nm2, bf16_t* __restrict__ aggF,
    float* __restrict__ sw, float* __restrict__ invd) {
  const int i = blockIdx.x, t = threadIdx.x;
  float acc = 0.f, ws = 0.f, nbs = 0.f;
#pragma unroll
  for (int j = 0; j < 16; ++j) {
    const float nb = (float)nbm[i * 16 + j];
    const float wj = nb * nm2[i * 16 + j];
    acc += wj * feats2[(size_t)(i * 16 + j) * 256 + t];
    ws += wj;
    nbs += nb;
  }
  aggF[(size_t)i * 256 + t] = f2bf(acc);
  if (t == 0) { sw[i] = ws; invd[i] = 1.f / fmaxf(nbs, 1.f); }
}

__global__ __launch_bounds__(256) void agg_state(
    const bf16_t* __restrict__ src, const int* __restrict__ nbm,
    bf16_t* __restrict__ agg) {
  const int i = blockIdx.x, t = threadIdx.x;
  float a0 = 0.f, a1 = 0.f, nbs = 0.f;
#pragma unroll
  for (int j = 0; j < 16; ++j) {
    const float nb = (float)nbm[i * 16 + j];
    const bf16_t* r = src + (size_t)(i * 16 + j) * 512;
    a0 += nb * bf2f(r[t]);
    a1 += nb * bf2f(r[t + 256]);
    nbs += nb;
  }
  const float inv = 1.f / fmaxf(nbs, 1.f);
  agg[(size_t)i * 512 + t] = f2bf(a0 * inv);
  agg[(size_t)i * 512 + 256 + t] = f2bf(a1 * inv);
}

__global__ void cvt_bf16(const float* __restrict__ src,
                         bf16_t* __restrict__ dst, int n4) {
  const int i = blockIdx.x * 256 + threadIdx.x;
  if (i < n4) {
    const float4 v = ((const float4*)src)[i];
    ushort4 o;
    o.x = f2bf(v.x); o.y = f2bf(v.y); o.z = f2bf(v.z); o.w = f2bf(v.w);
    ((ushort4*)dst)[i] = o;
  }
}

__global__ __launch_bounds__(256) void cls_k(
    const bf16_t* __restrict__ s, const float* __restrict__ wc,
    const float* __restrict__ bc, float* __restrict__ out) {
  __shared__ float srow[512];
  const int m = blockIdx.x, t = threadIdx.x;
  srow[t] = bf2f(s[(size_t)m * 512 + t]);
  srow[t + 256] = bf2f(s[(size_t)m * 512 + 256 + t]);
  __syncthreads();
  if (t < 47) {
    float a = bc[t];
    const float* wr = wc + (size_t)t * 512;
    for (int k = 0; k < 512; ++k) a += srow[k] * wr[k];
    out[(size_t)m * 47 + t] = a;
  }
}

// ---------------------------------------------------------------------------
struct LayerW {
  const bf16_t *wsage, *wqkv, *wout, *wf1, *wf2;
  const float *bsage, *bqkv, *bout, *bf1, *bf2;
  const float *n1g, *n1b, *n2g, *n2b;
};
struct Scratch {
  float* tmp;
  bf16_t *h1, *h2, *qkb, *vt, *attno, *f1o;
};

static void run_block(int n, const bf16_t* sf, const bf16_t* agg,
                      const float* nmask, const LayerW& L, const Scratch& S,
                      bf16_t* sout, hipStream_t st) {
  if (n == 4096) {
    mgemm<128, 128, 0, true><<<dim3(32, 4), 256, 0, st>>>(
        sf, agg, L.wsage, L.bsage, nullptr, nullptr, nullptr, S.tmp, nullptr,
        nullptr, n, 512, 1024);
  } else {
    mgemm<64, 64, 0, true><<<dim3(4, 8), 256, 0, st>>>(
        sf, agg, L.wsage, L.bsage, nullptr, nullptr, nullptr, S.tmp, nullptr,
        nullptr, n, 512, 1024);
  }
  add_ln<<<n, 256, 0, st>>>(sf, S.tmp, L.n1g, L.n1b, S.h1);
  if (n == 4096) {
    mgemm<128, 128, 5, false><<<dim3(32, 12), 256, 0, st>>>(
        S.h1, nullptr, L.wqkv, L.bqkv, nullptr, nullptr, nullptr, nullptr,
        S.qkb, S.vt, n, 1536, 512);
  } else {
    mgemm<64, 64, 5, false><<<dim3(4, 24), 256, 0, st>>>(
        S.h1, nullptr, L.wqkv, L.bqkv, nullptr, nullptr, nullptr, nullptr,
        S.qkb, S.vt, n, 1536, 512);
  }
  flashT<<<(n / 64) * 4, 256, 0, st>>>(S.qkb, S.vt, S.attno, n);
  if (n == 4096) {
    mgemm<128, 128, 0, false><<<dim3(32, 4), 256, 0, st>>>(
        S.attno, nullptr, L.wout, L.bout, nullptr, nullptr, nullptr, S.tmp,
        nullptr, nullptr, n, 512, 512);
  } else {
    mgemm<64, 64, 0, false><<<dim3(4, 8), 256, 0, st>>>(
        S.attno, nullptr, L.wout, L.bout, nullptr, nullptr, nullptr, S.tmp,
        nullptr, nullptr, n, 512, 512);
  }
  add_ln<<<n, 256, 0, st>>>(S.h1, S.tmp, L.n2g, L.n2b, S.h2);
  if (n == 4096) {
    mgemm<128, 128, 3, false><<<dim3(32, 8), 256, 0, st>>>(
        S.h2, nullptr, L.wf1, L.bf1, nullptr, nullptr, nullptr, nullptr, S.f1o,
        nullptr, n, 1024, 512);
    mgemm<128, 128, 4, false><<<dim3(32, 4), 256, 0, st>>>(
        S.f1o, nullptr, L.wf2, L.bf2, S.h2, nmask, nullptr, nullptr, sout,
        nullptr, n, 512, 1024);
  } else {
    mgemm<64, 64, 3, false><<<dim3(4, 16), 256, 0, st>>>(
        S.h2, nullptr, L.wf1, L.bf1, nullptr, nullptr, nullptr, nullptr, S.f1o,
        nullptr, n, 1024, 512);
    mgemm<64, 64, 4, false><<<dim3(4, 8), 256, 0, st>>>(
        S.f1o, nullptr, L.wf2, L.bf2, S.h2, nmask, nullptr, nullptr, sout,
        nullptr, n, 512, 1024);
  }
}

extern "C" void kernel_launch(void* const* d_in, const int* in_sizes, int n_in,
                              void* d_out, int out_size, void* d_ws,
                              size_t ws_size, hipStream_t stream) {
  const float* feats0 = (const float*)d_in[0];
  const float* feats1 = (const float*)d_in[1];
  const float* feats2 = (const float*)d_in[2];
  const float* nmask0 = (const float*)d_in[3];
  const float* nmask1 = (const float*)d_in[4];
  const float* nmask2 = (const float*)d_in[5];
  const int* nbmask0 = (const int*)d_in[6];
  const int* nbmask1 = (const int*)d_in[7];
  const float* emb_w = (const float*)d_in[8];
  const float* emb_b = (const float*)d_in[9];
  const float* sage_w = (const float*)d_in[10];
  const float* sage_b = (const float*)d_in[11];
  const float* qkv_w = (const float*)d_in[12];
  const float* qkv_b = (const float*)d_in[13];
  const float* out_w = (const float*)d_in[14];
  const float* out_b = (const float*)d_in[15];
  const float* n1_g = (const float*)d_in[16];
  const float* n1_b = (const float*)d_in[17];
  const float* n2_g = (const float*)d_in[18];
  const float* n2_b = (const float*)d_in[19];
  const float* ffn_w1 = (const float*)d_in[20];
  const float* ffn_b1 = (const float*)d_in[21];
  const float* ffn_w2 = (const float*)d_in[22];
  const float* ffn_b2 = (const float*)d_in[23];
  const float* cls_w = (const float*)d_in[24];
  const float* cls_b = (const float*)d_in[25];
  float* out = (float*)d_out;

  size_t off = 0;
  auto alloc = [&](size_t bytes) {
    void* r = (char*)d_ws + off;
    off += (bytes + 255) & ~(size_t)255;
    return r;
  };
  bf16_t* wemb = (bf16_t*)alloc((size_t)512 * 256 * 2);
  bf16_t* wsage = (bf16_t*)alloc((size_t)2 * 512 * 1024 * 2);
  bf16_t* wqkv = (bf16_t*)alloc((size_t)2 * 1536 * 512 * 2);
  bf16_t* wout = (bf16_t*)alloc((size_t)2 * 512 * 512 * 2);
  bf16_t* wf1 = (bf16_t*)alloc((size_t)2 * 1024 * 512 * 2);
  bf16_t* wf2 = (bf16_t*)alloc((size_t)2 * 512 * 1024 * 2);
  bf16_t* f0b = (bf16_t*)alloc((size_t)256 * 256 * 2);
  bf16_t* f1b = (bf16_t*)alloc((size_t)4096 * 256 * 2);
  bf16_t* s0 = (bf16_t*)alloc((size_t)256 * 512 * 2);
  bf16_t* s0b = (bf16_t*)alloc((size_t)256 * 512 * 2);
  bf16_t* s0f = (bf16_t*)alloc((size_t)256 * 512 * 2);
  bf16_t* s1 = (bf16_t*)alloc((size_t)4096 * 512 * 2);
  bf16_t* s1b = (bf16_t*)alloc((size_t)4096 * 512 * 2);
  bf16_t* aggFb = (bf16_t*)alloc((size_t)4096 * 256 * 2);
  float* swv = (float*)alloc((size_t)4096 * 4);
  float* invd = (float*)alloc((size_t)4096 * 4);
  bf16_t* aggb = (bf16_t*)alloc((size_t)4096 * 512 * 2);
  float* tmp = (float*)alloc((size_t)4096 * 512 * 4);
  bf16_t* h1 = (bf16_t*)alloc((size_t)4096 * 512 * 2);
  bf16_t* h2 = (bf16_t*)alloc((size_t)4096 * 512 * 2);
  bf16_t* qkb = (bf16_t*)alloc((size_t)4096 * 1024 * 2);
  bf16_t* vt = (bf16_t*)alloc((size_t)512 * 4096 * 2);
  bf16_t* attno = (bf16_t*)alloc((size_t)4096 * 512 * 2);
  bf16_t* f1o = (bf16_t*)alloc((size_t)4096 * 1024 * 2);

  auto CVT = [&](const float* s, bf16_t* d, int cnt) {
    cvt_bf16<<<(cnt / 4 + 255) / 256, 256, 0, stream>>>(s, d, cnt / 4);
  };
  CVT(emb_w, wemb, 512 * 256);
  CVT(sage_w, wsage, 2 * 512 * 1024);
  CVT(qkv_w, wqkv, 2 * 1536 * 512);
  CVT(out_w, wout, 2 * 512 * 512);
  CVT(ffn_w1, wf1, 2 * 1024 * 512);
  CVT(ffn_w2, wf2, 2 * 512 * 1024);
  CVT(feats0, f0b, 256 * 256);
  CVT(feats1, f1b, 4096 * 256);

  // embeddings (depth 2 folded into aggregation)
  mgemm<128, 128, 1, false><<<dim3(32, 4), 256, 0, stream>>>(
      f1b, nullptr, wemb, emb_b, nullptr, nmask1, nullptr, nullptr, s1, nullptr,
      4096, 512, 256);
  mgemm<64, 64, 1, false><<<dim3(4, 8), 256, 0, stream>>>(
      f0b, nullptr, wemb, emb_b, nullptr, nmask0, nullptr, nullptr, s0, nullptr,
      256, 512, 256);
  agg_feats<<<4096, 256, 0, stream>>>(feats2, nbmask1, nmask2, aggFb, swv, invd);
  mgemm<128, 128, 2, false><<<dim3(32, 4), 256, 0, stream>>>(
      aggFb, nullptr, wemb, emb_b, nullptr, swv, invd, nullptr, aggb, nullptr,
      4096, 512, 256);

  LayerW L0{wsage, wqkv, wout, wf1, wf2,
            sage_b, qkv_b, out_b, ffn_b1, ffn_b2,
            n1_g, n1_b, n2_g, n2_b};
  LayerW L1{wsage + 512 * 1024, wqkv + 1536 * 512, wout + 512 * 512,
            wf1 + 1024 * 512, wf2 + 512 * 1024,
            sage_b + 512, qkv_b + 1536, out_b + 512, ffn_b1 + 1024,
            ffn_b2 + 512, n1_g + 512, n1_b + 512, n2_g + 512, n2_b + 512};
  Scratch S{tmp, h1, h2, qkb, vt, attno, f1o};

  // layer 0, depth 1 (n=4096)
  run_block(4096, s1, aggb, nmask1, L0, S, s1b, stream);
  // layer 0, depth 0 (children = old s1)
  agg_state<<<256, 256, 0, stream>>>(s1, nbmask0, aggb);
  run_block(256, s0, aggb, nmask0, L0, S, s0b, stream);
  // layer 1, depth 0 (children = s1b)
  agg_state<<<256, 256, 0, stream>>>(s1b, nbmask0, aggb);
  run_block(256, s0b, aggb, nmask0, L1, S, s0f, stream);

  cls_k<<<256, 256, 0, stream>>>(s0f, cls_w, cls_b, out);
}

// Round 3
// 327.378 us; speedup vs baseline: 8.0625x; 1.1720x over previous
//
#include <hip/hip_runtime.h>
#include <math.h>

// ---------------------------------------------------------------------------
// GraphTransformer, bf16 MFMA version. Round 3: KV-split flash, exp2 softmax,
// setprio, grid retiling, fused weight conversion.
// NL=2, H=4, C=512, IN=256, F=16, B=256, NC=47, DH=128
// ---------------------------------------------------------------------------

typedef unsigned short bf16_t;
typedef __attribute__((ext_vector_type(8))) short bf16x8_t;
typedef __attribute__((ext_vector_type(4))) float f32x4_t;

__device__ __forceinline__ bf16_t f2bf(float f) {
  union { float f; unsigned u; } v; v.f = f;
  unsigned r = v.u + 0x7FFFu + ((v.u >> 16) & 1u);
  return (bf16_t)(r >> 16);
}
__device__ __forceinline__ float bf2f(bf16_t u) {
  union { unsigned u; float f; } v; v.u = ((unsigned)u) << 16; return v.f;
}
__device__ __forceinline__ void gload16(const void* g, void* l) {
  __builtin_amdgcn_global_load_lds(
      (const __attribute__((address_space(1))) unsigned int*)g,
      (__attribute__((address_space(3))) unsigned int*)l, 16, 0, 0);
}

// Q pre-scale: 1/sqrt(128) * log2(e)  (softmax runs in log2 domain)
#define QSCALE (0.08838834764831845f * 1.4426950408889634f)

// ---------------------------------------------------------------------------
// GEMM: C[M,N] = A[M,K] @ W[N,K]^T + epilogue. A,W bf16; accum fp32.
// MODE 0: Cf = acc + b                      (fp32 out)
// MODE 1: Cb = (acc + b) * rowa[m]          (embedding * nmask)
// MODE 2: Cb = (acc + b*rowa[m]) * rowb[m]  (agg-emb)
// MODE 3: Cb = relu(acc + b)                (ffn1)
// MODE 4: Cb = (acc + b + res[m,n]) * rowa[m]  (ffn2 + residual + nmask)
// MODE 5: qkv: n<512 -> Cb[m,1024]*QSCALE; <1024 -> Cb; >=1024 -> Vt[n-1024,m]
// SPLIT: A = concat(A[M,512], A2[M,512]) along K (K=1024).
// ---------------------------------------------------------------------------
template <int BM, int BN, int MODE, bool SPLIT>
__global__ __launch_bounds__(256) void mgemm(
    const bf16_t* __restrict__ A, const bf16_t* __restrict__ A2,
    const bf16_t* __restrict__ W, const float* __restrict__ bias,
    const bf16_t* __restrict__ res, const float* __restrict__ rowa,
    const float* __restrict__ rowb, float* __restrict__ Cf,
    bf16_t* __restrict__ Cb, bf16_t* __restrict__ Vt,
    int M, int N, int K) {
  constexpr int FM = BM / 32, FN = BN / 32;
  constexpr int NCH = (BM + BN) / 16;  // 1KB staging chunks per k-step
  constexpr int CPW = NCH / 4;
  __shared__ bf16_t lds[2][(BM + BN) * 32];
  const int t = threadIdx.x;
  const int w = t >> 6, lane = t & 63;
  const int g = lane >> 4, li = lane & 15;
  const int bm = blockIdx.x * BM, bn = blockIdx.y * BN;
  const int wr = (w >> 1) * (BM / 2), wc = (w & 1) * (BN / 2);
  f32x4_t acc[FM][FN] = {};

  auto stage = [&](int buf, int k0) {
#pragma unroll
    for (int c0 = 0; c0 < CPW; ++c0) {
      const int c = w * CPW + c0;
      const int row = c * 16 + (lane >> 2);
      const int gk = k0 + (lane & 3) * 8;
      const bf16_t* src;
      if (row < BM) {
        if (SPLIT) {
          src = (gk < 512) ? (A + (size_t)(bm + row) * 512 + gk)
                           : (A2 + (size_t)(bm + row) * 512 + (gk - 512));
        } else {
          src = A + (size_t)(bm + row) * K + gk;
        }
      } else {
        src = W + (size_t)(bn + row - BM) * K + gk;
      }
      gload16(src, &lds[buf][c * 512]);
    }
  };

  const int nk = K / 32;
  stage(0, 0);
  for (int ks = 0; ks < nk; ++ks) {
    __syncthreads();
    if (ks + 1 < nk) stage((ks + 1) & 1, (ks + 1) * 32);
    const bf16_t* As = &lds[ks & 1][0];
    const bf16_t* Bs = &lds[ks & 1][BM * 32];
    bf16x8_t af[FM], bfr[FN];
#pragma unroll
    for (int i = 0; i < FM; ++i)
      af[i] = *(const bf16x8_t*)(As + (wr + i * 16 + li) * 32 + g * 8);
#pragma unroll
    for (int j = 0; j < FN; ++j)
      bfr[j] = *(const bf16x8_t*)(Bs + (wc + j * 16 + li) * 32 + g * 8);
#pragma unroll
    for (int i = 0; i < FM; ++i)
#pragma unroll
      for (int j = 0; j < FN; ++j)
        acc[i][j] = __builtin_amdgcn_mfma_f32_16x16x32_bf16(
            af[i], bfr[j], acc[i][j], 0, 0, 0);
  }

  // epilogue: D frag: col n = li, row m = g*4 + reg (verified layout)
#pragma unroll
  for (int i = 0; i < FM; ++i) {
    const int mb = bm + wr + i * 16 + g * 4;
#pragma unroll
    for (int j = 0; j < FN; ++j) {
      const int n = bn + wc + j * 16 + li;
      if (MODE == 5) {
        const float bb = bias[n];
        if (n < 512) {
#pragma unroll
          for (int r = 0; r < 4; ++r)
            Cb[(size_t)(mb + r) * 1024 + n] = f2bf((acc[i][j][r] + bb) * QSCALE);
        } else if (n < 1024) {
#pragma unroll
          for (int r = 0; r < 4; ++r)
            Cb[(size_t)(mb + r) * 1024 + n] = f2bf(acc[i][j][r] + bb);
        } else {
          ushort4 o;
          o.x = f2bf(acc[i][j][0] + bb); o.y = f2bf(acc[i][j][1] + bb);
          o.z = f2bf(acc[i][j][2] + bb); o.w = f2bf(acc[i][j][3] + bb);
          *(ushort4*)(Vt + (size_t)(n - 1024) * M + mb) = o;
        }
      } else {
#pragma unroll
        for (int r = 0; r < 4; ++r) {
          const int m = mb + r;
          const float v = acc[i][j][r];
          if (MODE == 0) Cf[(size_t)m * N + n] = v + bias[n];
          if (MODE == 1) Cb[(size_t)m * N + n] = f2bf((v + bias[n]) * rowa[m]);
          if (MODE == 2)
            Cb[(size_t)m * N + n] = f2bf((v + bias[n] * rowa[m]) * rowb[m]);
          if (MODE == 3) Cb[(size_t)m * N + n] = f2bf(fmaxf(v + bias[n], 0.f));
          if (MODE == 4)
            Cb[(size_t)m * N + n] =
                f2bf((v + bias[n] + bf2f(res[(size_t)m * N + n])) * rowa[m]);
        }
      }
    }
  }
}

// ---------------------------------------------------------------------------
// Flash attention, swapped-operand form with KV split.
// qk: [N][1024] = Q*QSCALE|K, head h at cols h*128. vt: [512][N] = V^T.
// bid = qb*(4*SPLITS) + h*SPLITS + s  (consecutive bids = distinct (h,s) ->
// distinct XCDs; each (h,s) K/V half stays in one XCD's L2).
// SPLITS==1: normalized bf16 out to attno.
// SPLITS==2: unnormalized fp32 acc to Of[s][q][512], (m,l) to Ml[(s*4+h)*N+q].
// ---------------------------------------------------------------------------
template <int SPLITS>
__global__ __launch_bounds__(256) void flashT(
    const bf16_t* __restrict__ qk, const bf16_t* __restrict__ vt,
    bf16_t* __restrict__ attno, float* __restrict__ Of,
    float* __restrict__ Ml, int N) {
  __shared__ bf16_t Ks[2][64 * 128];
  __shared__ bf16_t Vs[2][128 * 64];
  __shared__ bf16_t Ps[4][16 * 64];
  const int bid = blockIdx.x;
  const int sp = bid % SPLITS;
  const int h = (bid / SPLITS) & 3;
  const int qb = bid / (4 * SPLITS);
  const int t = threadIdx.x, w = t >> 6, lane = t & 63;
  const int g = lane >> 4, li = lane & 15;
  const int kvbase = sp * (N / SPLITS);
  const int nt = (N / SPLITS) >> 6;

  bf16x8_t qf[4];
  {
    const bf16_t* qrow = qk + (size_t)(qb * 64 + w * 16 + li) * 1024 + h * 128;
#pragma unroll
    for (int ks = 0; ks < 4; ++ks)
      qf[ks] = *(const bf16x8_t*)(qrow + ks * 32 + g * 8);
  }

  auto stage = [&](int buf, int kv0) {
#pragma unroll
    for (int i = 0; i < 4; ++i) {
      const int c = w * 4 + i;
      {  // K tile: 64 rows(kv) x 128 d, xor-swizzled 16B chunks
        const int row = c * 4 + (lane >> 4);
        const int col = ((lane & 15) ^ (row & 7)) * 8;
        gload16(qk + (size_t)(kv0 + row) * 1024 + 512 + h * 128 + col,
                &Ks[buf][c * 512]);
      }
      {  // Vt tile: 128 rows(d) x 64 kv, xor-swizzled
        const int row = c * 8 + (lane >> 3);
        const int col = ((lane & 7) ^ (row & 7)) * 8;
        gload16(vt + (size_t)(h * 128 + row) * N + kv0 + col,
                &Vs[buf][c * 512]);
      }
    }
  };

  f32x4_t acc[8] = {};
  float mrun = -1e30f, lrun = 0.f;
  stage(0, kvbase);
  for (int tt = 0; tt < nt; ++tt) {
    const int cur = tt & 1;
    __syncthreads();
    if (tt + 1 < nt) stage(cur ^ 1, kvbase + (tt + 1) * 64);

    // S^T = K · Q^T : frag row kv = mf*16+g*4+r, col q = li
    f32x4_t sf[4] = {};
    __builtin_amdgcn_s_setprio(1);
#pragma unroll
    for (int ks = 0; ks < 4; ++ks) {
#pragma unroll
      for (int mf = 0; mf < 4; ++mf) {
        const bf16x8_t kf = *(const bf16x8_t*)(
            &Ks[cur][(mf * 16 + li) * 128 + (((ks * 4 + g) ^ (li & 7)) << 3)]);
        sf[mf] =
            __builtin_amdgcn_mfma_f32_16x16x32_bf16(kf, qf[ks], sf[mf], 0, 0, 0);
      }
    }
    __builtin_amdgcn_s_setprio(0);
    // online softmax in log2 domain: lane li owns q-row li
    float tmax = -1e30f;
#pragma unroll
    for (int mf = 0; mf < 4; ++mf)
#pragma unroll
      for (int r = 0; r < 4; ++r) tmax = fmaxf(tmax, sf[mf][r]);
    tmax = fmaxf(tmax, __shfl_xor(tmax, 16));
    tmax = fmaxf(tmax, __shfl_xor(tmax, 32));
    const float mnew = fmaxf(mrun, tmax);
    const float fsc = exp2f(mrun - mnew);
    mrun = mnew;
    float lsum = 0.f;
#pragma unroll
    for (int mf = 0; mf < 4; ++mf)
#pragma unroll
      for (int r = 0; r < 4; ++r) {
        const float p = exp2f(sf[mf][r] - mnew);
        sf[mf][r] = p;
        lsum += p;
      }
    lsum += __shfl_xor(lsum, 16);
    lsum += __shfl_xor(lsum, 32);
    lrun = lrun * fsc + lsum;
#pragma unroll
    for (int mf = 0; mf < 8; ++mf) acc[mf] *= fsc;

    // P -> per-wave LDS (bf16, swizzled); chunk c holds kv c*8..c*8+7
#pragma unroll
    for (int mf = 0; mf < 4; ++mf) {
      uint2 pv;
      pv.x = (unsigned)f2bf(sf[mf][0]) | ((unsigned)f2bf(sf[mf][1]) << 16);
      pv.y = (unsigned)f2bf(sf[mf][2]) | ((unsigned)f2bf(sf[mf][3]) << 16);
      *(uint2*)(&Ps[w][li * 64 + ((((mf * 2) + (g >> 1)) ^ (li & 7)) << 3) +
                       ((g & 1) << 2)]) = pv;
    }
    // O^T += Vt · P^T
    __builtin_amdgcn_s_setprio(1);
#pragma unroll
    for (int ks = 0; ks < 2; ++ks) {
      const bf16x8_t pf = *(const bf16x8_t*)(
          &Ps[w][li * 64 + (((ks * 4 + g) ^ (li & 7)) << 3)]);
#pragma unroll
      for (int mf = 0; mf < 8; ++mf) {
        const bf16x8_t vf = *(const bf16x8_t*)(
            &Vs[cur][(mf * 16 + li) * 64 + (((ks * 4 + g) ^ (li & 7)) << 3)]);
        acc[mf] =
            __builtin_amdgcn_mfma_f32_16x16x32_bf16(vf, pf, acc[mf], 0, 0, 0);
      }
    }
    __builtin_amdgcn_s_setprio(0);
  }

  if (SPLITS == 1) {
    const float invl = 1.f / lrun;
#pragma unroll
    for (int mf = 0; mf < 8; ++mf) {
      ushort4 o;
      o.x = f2bf(acc[mf][0] * invl); o.y = f2bf(acc[mf][1] * invl);
      o.z = f2bf(acc[mf][2] * invl); o.w = f2bf(acc[mf][3] * invl);
      *(ushort4*)(attno + (size_t)(qb * 64 + w * 16 + li) * 512 + h * 128 +
                  mf * 16 + g * 4) = o;
    }
  } else {
    const int q = qb * 64 + w * 16 + li;
#pragma unroll
    for (int mf = 0; mf < 8; ++mf)
      *(f32x4_t*)(Of + ((size_t)sp * N + q) * 512 + h * 128 + mf * 16 + g * 4) =
          acc[mf];
    if (lane < 16) {
      float2 ml; ml.x = mrun; ml.y = lrun;
      *(float2*)(Ml + ((size_t)(sp * 4 + h) * N + q) * 2) = ml;
    }
  }
}

// merge 2 KV-splits: out = sum_s O_s * 2^(m_s-m) / sum_s l_s * 2^(m_s-m)
__global__ __launch_bounds__(256) void merge_attn(
    const float* __restrict__ Of, const float* __restrict__ Ml,
    bf16_t* __restrict__ attno, int N) {
  const int q = blockIdx.x, t = threadIdx.x;
#pragma unroll
  for (int half = 0; half < 2; ++half) {
    const int c = t + half * 256;
    const int h = c >> 7;
    const float2 a = ((const float2*)Ml)[(0 * 4 + h) * N + q];
    const float2 b = ((const float2*)Ml)[(1 * 4 + h) * N + q];
    const float m = fmaxf(a.x, b.x);
    const float w0 = exp2f(a.x - m), w1 = exp2f(b.x - m);
    const float num = Of[(size_t)q * 512 + c] * w0 +
                      Of[((size_t)N + q) * 512 + c] * w1;
    attno[(size_t)q * 512 + c] = f2bf(num / (a.y * w0 + b.y * w1));
  }
}

// ---------------------------------------------------------------------------
__global__ __launch_bounds__(256) void add_ln(
    const bf16_t* __restrict__ X, const float* __restrict__ Y,
    const float* __restrict__ gg, const float* __restrict__ bb,
    bf16_t* __restrict__ out) {
  const int row = blockIdx.x, t = threadIdx.x;
  const size_t base = (size_t)row * 512;
  const float x0 = bf2f(X[base + t]) + Y[base + t];
  const float x1 = bf2f(X[base + 256 + t]) + Y[base + 256 + t];
  float s = x0 + x1, ss = x0 * x0 + x1 * x1;
#pragma unroll
  for (int o = 32; o > 0; o >>= 1) {
    s += __shfl_down(s, o);
    ss += __shfl_down(ss, o);
  }
  __shared__ float rs[4], rss[4], sm[2];
  const int wv = t >> 6, ln = t & 63;
  if (ln == 0) { rs[wv] = s; rss[wv] = ss; }
  __syncthreads();
  if (t == 0) {
    const float S = rs[0] + rs[1] + rs[2] + rs[3];
    const float SS = rss[0] + rss[1] + rss[2] + rss[3];
    const float mean = S * (1.f / 512.f);
    sm[0] = mean;
    sm[1] = rsqrtf(SS * (1.f / 512.f) - mean * mean + 1e-5f);
  }
  __syncthreads();
  const float mean = sm[0], rstd = sm[1];
  out[base + t] = f2bf((x0 - mean) * rstd * gg[t] + bb[t]);
  out[base + 256 + t] = f2bf((x1 - mean) * rstd * gg[t + 256] + bb[t + 256]);
}

__global__ __launch_bounds__(256) void agg_feats(
    const float* __restrict__ feats2, const int* __restrict__ nbm,
    const float* __restrict__ nm2, bf16_t* __restrict__ aggF,
    float* __restrict__ sw, float* __restrict__ invd) {
  const int i = blockIdx.x, t = threadIdx.x;
  float acc = 0.f, ws = 0.f, nbs = 0.f;
#pragma unroll
  for (int j = 0; j < 16; ++j) {
    const float nb = (float)nbm[i * 16 + j];
    const float wj = nb * nm2[i * 16 + j];
    acc += wj * feats2[(size_t)(i * 16 + j) * 256 + t];
    ws += wj;
    nbs += nb;
  }
  aggF[(size_t)i * 256 + t] = f2bf(acc);
  if (t == 0) { sw[i] = ws; invd[i] = 1.f / fmaxf(nbs, 1.f); }
}

__global__ __launch_bounds__(256) void agg_state(
    const bf16_t* __restrict__ src, const int* __restrict__ nbm,
    bf16_t* __restrict__ agg) {
  const int i = blockIdx.x, t = threadIdx.x;
  float a0 = 0.f, a1 = 0.f, nbs = 0.f;
#pragma unroll
  for (int j = 0; j < 16; ++j) {
    const float nb = (float)nbm[i * 16 + j];
    const bf16_t* r = src + (size_t)(i * 16 + j) * 512;
    a0 += nb * bf2f(r[t]);
    a1 += nb * bf2f(r[t + 256]);
    nbs += nb;
  }
  const float inv = 1.f / fmaxf(nbs, 1.f);
  agg[(size_t)i * 512 + t] = f2bf(a0 * inv);
  agg[(size_t)i * 512 + 256 + t] = f2bf(a1 * inv);
}

// all weight/feature fp32->bf16 conversions in one dispatch.
// segment boundaries in float4 units (compile-time):
//   emb 32768 | sage 262144 | qkv 393216 | out 131072 | f1 262144 | f2 262144
//   | feats0 16384 | feats1 262144   (total 1622016 -> grid 6336 x 256)
__global__ __launch_bounds__(256) void cvt_all(
    const float* __restrict__ s_emb, const float* __restrict__ s_sage,
    const float* __restrict__ s_qkv, const float* __restrict__ s_out,
    const float* __restrict__ s_f1, const float* __restrict__ s_f2,
    const float* __restrict__ s_ft0, const float* __restrict__ s_ft1,
    bf16_t* __restrict__ d_emb, bf16_t* __restrict__ d_sage,
    bf16_t* __restrict__ d_qkv, bf16_t* __restrict__ d_out,
    bf16_t* __restrict__ d_f1, bf16_t* __restrict__ d_f2,
    bf16_t* __restrict__ d_ft0, bf16_t* __restrict__ d_ft1) {
  int i = blockIdx.x * 256 + threadIdx.x;
  const float* s; bf16_t* d; int base;
  if (i < 32768)        { s = s_emb;  d = d_emb;  base = 0; }
  else if (i < 294912)  { s = s_sage; d = d_sage; base = 32768; }
  else if (i < 688128)  { s = s_qkv;  d = d_qkv;  base = 294912; }
  else if (i < 819200)  { s = s_out;  d = d_out;  base = 688128; }
  else if (i < 1081344) { s = s_f1;   d = d_f1;   base = 819200; }
  else if (i < 1343488) { s = s_f2;   d = d_f2;   base = 1081344; }
  else if (i < 1359872) { s = s_ft0;  d = d_ft0;  base = 1343488; }
  else                  { s = s_ft1;  d = d_ft1;  base = 1359872; }
  i -= base;
  const float4 v = ((const float4*)s)[i];
  ushort4 o;
  o.x = f2bf(v.x); o.y = f2bf(v.y); o.z = f2bf(v.z); o.w = f2bf(v.w);
  ((ushort4*)d)[i] = o;
}

__global__ __launch_bounds__(256) void cls_k(
    const bf16_t* __restrict__ s, const float* __restrict__ wc,
    const float* __restrict__ bc, float* __restrict__ out) {
  __shared__ float srow[512];
  const int m = blockIdx.x, t = threadIdx.x;
  srow[t] = bf2f(s[(size_t)m * 512 + t]);
  srow[t + 256] = bf2f(s[(size_t)m * 512 + 256 + t]);
  __syncthreads();
  if (t < 47) {
    float a = bc[t];
    const float* wr = wc + (size_t)t * 512;
    for (int k = 0; k < 512; ++k) a += srow[k] * wr[k];
    out[(size_t)m * 47 + t] = a;
  }
}

// ---------------------------------------------------------------------------
struct LayerW {
  const bf16_t *wsage, *wqkv, *wout, *wf1, *wf2;
  const float *bsage, *bqkv, *bout, *bf1, *bf2;
  const float *n1g, *n1b, *n2g, *n2b;
};
struct Scratch {
  float* tmp;
  bf16_t *h1, *h2, *qkb, *vt, *attno, *f1o;
  float *Of, *Ml;
};

static void run_block(int n, const bf16_t* sf, const bf16_t* agg,
                      const float* nmask, const LayerW& L, const Scratch& S,
                      bf16_t* sout, hipStream_t st) {
  if (n == 4096) {
    mgemm<64, 128, 0, true><<<dim3(64, 4), 256, 0, st>>>(
        sf, agg, L.wsage, L.bsage, nullptr, nullptr, nullptr, S.tmp, nullptr,
        nullptr, n, 512, 1024);
  } else {
    mgemm<64, 64, 0, true><<<dim3(4, 8), 256, 0, st>>>(
        sf, agg, L.wsage, L.bsage, nullptr, nullptr, nullptr, S.tmp, nullptr,
        nullptr, n, 512, 1024);
  }
  add_ln<<<n, 256, 0, st>>>(sf, S.tmp, L.n1g, L.n1b, S.h1);
  if (n == 4096) {
    mgemm<128, 128, 5, false><<<dim3(32, 12), 256, 0, st>>>(
        S.h1, nullptr, L.wqkv, L.bqkv, nullptr, nullptr, nullptr, nullptr,
        S.qkb, S.vt, n, 1536, 512);
    flashT<2><<<(n / 64) * 8, 256, 0, st>>>(S.qkb, S.vt, nullptr, S.Of, S.Ml, n);
    merge_attn<<<n, 256, 0, st>>>(S.Of, S.Ml, S.attno, n);
    mgemm<64, 128, 0, false><<<dim3(64, 4), 256, 0, st>>>(
        S.attno, nullptr, L.wout, L.bout, nullptr, nullptr, nullptr, S.tmp,
        nullptr, nullptr, n, 512, 512);
  } else {
    mgemm<64, 64, 5, false><<<dim3(4, 24), 256, 0, st>>>(
        S.h1, nullptr, L.wqkv, L.bqkv, nullptr, nullptr, nullptr, nullptr,
        S.qkb, S.vt, n, 1536, 512);
    flashT<1><<<(n / 64) * 4, 256, 0, st>>>(S.qkb, S.vt, S.attno, nullptr,
                                            nullptr, n);
    mgemm<64, 64, 0, false><<<dim3(4, 8), 256, 0, st>>>(
        S.attno, nullptr, L.wout, L.bout, nullptr, nullptr, nullptr, S.tmp,
        nullptr, nullptr, n, 512, 512);
  }
  add_ln<<<n, 256, 0, st>>>(S.h1, S.tmp, L.n2g, L.n2b, S.h2);
  if (n == 4096) {
    mgemm<128, 128, 3, false><<<dim3(32, 8), 256, 0, st>>>(
        S.h2, nullptr, L.wf1, L.bf1, nullptr, nullptr, nullptr, nullptr, S.f1o,
        nullptr, n, 1024, 512);
    mgemm<64, 128, 4, false><<<dim3(64, 4), 256, 0, st>>>(
        S.f1o, nullptr, L.wf2, L.bf2, S.h2, nmask, nullptr, nullptr, sout,
        nullptr, n, 512, 1024);
  } else {
    mgemm<64, 64, 3, false><<<dim3(4, 16), 256, 0, st>>>(
        S.h2, nullptr, L.wf1, L.bf1, nullptr, nullptr, nullptr, nullptr, S.f1o,
        nullptr, n, 1024, 512);
    mgemm<64, 64, 4, false><<<dim3(4, 8), 256, 0, st>>>(
        S.f1o, nullptr, L.wf2, L.bf2, S.h2, nmask, nullptr, nullptr, sout,
        nullptr, n, 512, 1024);
  }
}

extern "C" void kernel_launch(void* const* d_in, const int* in_sizes, int n_in,
                              void* d_out, int out_size, void* d_ws,
                              size_t ws_size, hipStream_t stream) {
  const float* feats0 = (const float*)d_in[0];
  const float* feats1 = (const float*)d_in[1];
  const float* feats2 = (const float*)d_in[2];
  const float* nmask0 = (const float*)d_in[3];
  const float* nmask1 = (const float*)d_in[4];
  const float* nmask2 = (const float*)d_in[5];
  const int* nbmask0 = (const int*)d_in[6];
  const int* nbmask1 = (const int*)d_in[7];
  const float* emb_w = (const float*)d_in[8];
  const float* emb_b = (const float*)d_in[9];
  const float* sage_w = (const float*)d_in[10];
  const float* sage_b = (const float*)d_in[11];
  const float* qkv_w = (const float*)d_in[12];
  const float* qkv_b = (const float*)d_in[13];
  const float* out_w = (const float*)d_in[14];
  const float* out_b = (const float*)d_in[15];
  const float* n1_g = (const float*)d_in[16];
  const float* n1_b = (const float*)d_in[17];
  const float* n2_g = (const float*)d_in[18];
  const float* n2_b = (const float*)d_in[19];
  const float* ffn_w1 = (const float*)d_in[20];
  const float* ffn_b1 = (const float*)d_in[21];
  const float* ffn_w2 = (const float*)d_in[22];
  const float* ffn_b2 = (const float*)d_in[23];
  const float* cls_w = (const float*)d_in[24];
  const float* cls_b = (const float*)d_in[25];
  float* out = (float*)d_out;

  size_t off = 0;
  auto alloc = [&](size_t bytes) {
    void* r = (char*)d_ws + off;
    off += (bytes + 255) & ~(size_t)255;
    return r;
  };
  bf16_t* wemb = (bf16_t*)alloc((size_t)512 * 256 * 2);
  bf16_t* wsage = (bf16_t*)alloc((size_t)2 * 512 * 1024 * 2);
  bf16_t* wqkv = (bf16_t*)alloc((size_t)2 * 1536 * 512 * 2);
  bf16_t* wout = (bf16_t*)alloc((size_t)2 * 512 * 512 * 2);
  bf16_t* wf1 = (bf16_t*)alloc((size_t)2 * 1024 * 512 * 2);
  bf16_t* wf2 = (bf16_t*)alloc((size_t)2 * 512 * 1024 * 2);
  bf16_t* f0b = (bf16_t*)alloc((size_t)256 * 256 * 2);
  bf16_t* f1b = (bf16_t*)alloc((size_t)4096 * 256 * 2);
  bf16_t* s0 = (bf16_t*)alloc((size_t)256 * 512 * 2);
  bf16_t* s0b = (bf16_t*)alloc((size_t)256 * 512 * 2);
  bf16_t* s0f = (bf16_t*)alloc((size_t)256 * 512 * 2);
  bf16_t* s1 = (bf16_t*)alloc((size_t)4096 * 512 * 2);
  bf16_t* s1b = (bf16_t*)alloc((size_t)4096 * 512 * 2);
  bf16_t* aggFb = (bf16_t*)alloc((size_t)4096 * 256 * 2);
  float* swv = (float*)alloc((size_t)4096 * 4);
  float* invd = (float*)alloc((size_t)4096 * 4);
  bf16_t* aggb = (bf16_t*)alloc((size_t)4096 * 512 * 2);
  float* tmp = (float*)alloc((size_t)4096 * 512 * 4);
  bf16_t* h1 = (bf16_t*)alloc((size_t)4096 * 512 * 2);
  bf16_t* h2 = (bf16_t*)alloc((size_t)4096 * 512 * 2);
  bf16_t* qkb = (bf16_t*)alloc((size_t)4096 * 1024 * 2);
  bf16_t* vt = (bf16_t*)alloc((size_t)512 * 4096 * 2);
  bf16_t* attno = (bf16_t*)alloc((size_t)4096 * 512 * 2);
  bf16_t* f1o = (bf16_t*)alloc((size_t)4096 * 1024 * 2);
  float* Of = (float*)alloc((size_t)2 * 4096 * 512 * 4);
  float* Ml = (float*)alloc((size_t)2 * 4 * 4096 * 2 * 4);

  cvt_all<<<6336, 256, 0, stream>>>(emb_w, sage_w, qkv_w, out_w, ffn_w1,
                                    ffn_w2, feats0, feats1, wemb, wsage, wqkv,
                                    wout, wf1, wf2, f0b, f1b);

  // embeddings (depth 2 folded into aggregation)
  mgemm<64, 128, 1, false><<<dim3(64, 4), 256, 0, stream>>>(
      f1b, nullptr, wemb, emb_b, nullptr, nmask1, nullptr, nullptr, s1, nullptr,
      4096, 512, 256);
  mgemm<64, 64, 1, false><<<dim3(4, 8), 256, 0, stream>>>(
      f0b, nullptr, wemb, emb_b, nullptr, nmask0, nullptr, nullptr, s0, nullptr,
      256, 512, 256);
  agg_feats<<<4096, 256, 0, stream>>>(feats2, nbmask1, nmask2, aggFb, swv, invd);
  mgemm<64, 128, 2, false><<<dim3(64, 4), 256, 0, stream>>>(
      aggFb, nullptr, wemb, emb_b, nullptr, swv, invd, nullptr, aggb, nullptr,
      4096, 512, 256);

  LayerW L0{wsage, wqkv, wout, wf1, wf2,
            sage_b, qkv_b, out_b, ffn_b1, ffn_b2,
            n1_g, n1_b, n2_g, n2_b};
  LayerW L1{wsage + 512 * 1024, wqkv + 1536 * 512, wout + 512 * 512,
            wf1 + 1024 * 512, wf2 + 512 * 1024,
            sage_b + 512, qkv_b + 1536, out_b + 512, ffn_b1 + 1024,
            ffn_b2 + 512, n1_g + 512, n1_b + 512, n2_g + 512, n2_b + 512};
  Scratch S{tmp, h1, h2, qkb, vt, attno, f1o, Of, Ml};

  // layer 0, depth 1 (n=4096)
  run_block(4096, s1, aggb, nmask1, L0, S, s1b, stream);
  // layer 0, depth 0 (children = old s1)
  agg_state<<<256, 256, 0, stream>>>(s1, nbmask0, aggb);
  run_block(256, s0, aggb, nmask0, L0, S, s0b, stream);
  // layer 1, depth 0 (children = s1b)
  agg_state<<<256, 256, 0, stream>>>(s1b, nbmask0, aggb);
  run_block(256, s0b, aggb, nmask0, L1, S, s0f, stream);

  cls_k<<<256, 256, 0, stream>>>(s0f, cls_w, cls_b, out);
}